// Round 2
// baseline (643.938 us; speedup 1.0000x reference)
//
#include <hip/hip_runtime.h>
#include <hip/hip_bf16.h>

typedef __hip_bfloat16 bf16;

#define DEVI __device__ __forceinline__

DEVI float b2f(bf16 v) { return __bfloat162float(v); }
DEVI bf16 f2b(float v) { return __float2bfloat16(v); }
DEVI unsigned short f2bu(float v) {
    bf16 h = __float2bfloat16(v);
    unsigned short u;
    __builtin_memcpy(&u, &h, 2);
    return u;
}
DEVI float sigmoidf_(float z) { return 1.0f / (1.0f + __expf(-z)); }

// Problem constants
// B=8, H=W=56, C=192, WS=4 -> 14x14 windows, 1568 rows, ind=3072, hid=ncl=256
// ALL inputs/outputs are float32 (per reference setup_inputs / return dtypes).

// ---------------------------------------------------------------------------
// K0a: inc bitmask.  inc = (inc_w > 0)  (sigmoid(w)>0.5 <=> w>0).
// mask layout transposed: [word(16)][clause(256)]
__global__ __launch_bounds__(256) void inc_mask_kernel(const float* __restrict__ inc_w,
                                                       unsigned* __restrict__ mask) {
    int wi = blockIdx.x;   // 0..15 (which 32-bit word of the 512 literals)
    int cl = threadIdx.x;  // 0..255
    unsigned bits = 0u;
    int base = cl * 512 + wi * 32;
#pragma unroll
    for (int b = 0; b < 32; b++) {
        if (inc_w[base + b] > 0.0f) bits |= (1u << b);
    }
    mask[wi * 256 + cl] = bits;
}

// ---------------------------------------------------------------------------
// K0b: VW2 = vote_w @ W2 / 16   (256 x 3072, K=192), fp32 out
// (logits are not an output, so GEMM2+GEMM3 collapse into one K=256 GEMM)
__global__ __launch_bounds__(256) void vw2_kernel(const float* __restrict__ vote_w,
                                                  const float* __restrict__ W2,
                                                  float* __restrict__ vw2) {
    int n = blockIdx.x * 256 + threadIdx.x;  // 0..3071
    int k = blockIdx.y;                      // 0..255
    float acc = 0.0f;
    for (int j = 0; j < 192; j++) {
        acc = fmaf(vote_w[k * 192 + j], W2[j * 3072 + n], acc);
    }
    vw2[k * 3072 + n] = acc * 0.0625f;  // 1/sqrt(256)
}

// ---------------------------------------------------------------------------
// K1: LayerNorm + roll(-2,-2) + window partition -> win (1568 x 3072) bf16
__global__ __launch_bounds__(64) void ln_win_kernel(const float* __restrict__ x,
                                                    const float* __restrict__ gamma,
                                                    const float* __restrict__ beta,
                                                    bf16* __restrict__ win) {
    int blk = blockIdx.x;          // b*3136 + h'*56 + w'  (rolled coords)
    int w_ = blk % 56;
    int t2 = blk / 56;
    int h_ = t2 % 56;
    int b = t2 / 56;
    int hs = h_ + 2; if (hs >= 56) hs -= 56;
    int ws = w_ + 2; if (ws >= 56) ws -= 56;
    const float* xp = x + (((b * 56 + hs) * 56 + ws) * 192);
    int t = threadIdx.x;  // 0..63
    float v0 = xp[t];
    float v1 = xp[t + 64];
    float v2 = xp[t + 128];
    float s = v0 + v1 + v2;
    float sq = v0 * v0 + v1 * v1 + v2 * v2;
#pragma unroll
    for (int m = 1; m < 64; m <<= 1) {
        s += __shfl_xor(s, m, 64);
        sq += __shfl_xor(sq, m, 64);
    }
    float mean = s * (1.0f / 192.0f);
    float var = sq * (1.0f / 192.0f) - mean * mean;
    float inv = rsqrtf(var + 1e-5f);
    int row = b * 196 + (h_ >> 2) * 14 + (w_ >> 2);
    int fb = ((h_ & 3) * 4 + (w_ & 3)) * 192;
    bf16* wp = win + row * 3072 + fb;
    wp[t]       = f2b((v0 - mean) * inv * gamma[t]       + beta[t]);
    wp[t + 64]  = f2b((v1 - mean) * inv * gamma[t + 64]  + beta[t + 64]);
    wp[t + 128] = f2b((v2 - mean) * inv * gamma[t + 128] + beta[t + 128]);
}

// ---------------------------------------------------------------------------
// K2: tm_in = sigmoid(win @ W1 + b1).  M=1568, N=256, K=3072.
// Block: 8 rows x 128 cols, 2-way K-split within block. grid (2 coltiles, 196 rowtiles)
__global__ __launch_bounds__(256) void gemm1_kernel(const bf16* __restrict__ win,
                                                    const float* __restrict__ W1,
                                                    const float* __restrict__ b1,
                                                    float* __restrict__ tm_in) {
    __shared__ float a_s[2][8][64];     // [k-half][row][k]
    __shared__ float part[8][128];
    int t = threadIdx.x;
    int kh = t >> 7;          // 0 or 1
    int col = t & 127;
    int c0 = blockIdx.x * 128;
    int r0 = blockIdx.y * 8;
    float acc[8];
#pragma unroll
    for (int r = 0; r < 8; r++) acc[r] = 0.0f;

    for (int k0 = 0; k0 < 1536; k0 += 64) {
        // stage win[8 rows][both k-halves, 64 each] : 1024 floats / 256 threads
#pragma unroll
        for (int i = 0; i < 4; i++) {
            int idx = t + i * 256;
            int hh = idx >> 9;
            int r = (idx >> 6) & 7;
            int kk = idx & 63;
            a_s[hh][r][kk] = b2f(win[(r0 + r) * 3072 + hh * 1536 + k0 + kk]);
        }
        __syncthreads();
        int kbase = kh * 1536 + k0;
        for (int kk = 0; kk < 64; kk++) {
            float w = W1[(kbase + kk) * 256 + c0 + col];
#pragma unroll
            for (int r = 0; r < 8; r++) acc[r] = fmaf(a_s[kh][r][kk], w, acc[r]);
        }
        __syncthreads();
    }
    if (kh == 1) {
#pragma unroll
        for (int r = 0; r < 8; r++) part[r][col] = acc[r];
    }
    __syncthreads();
    if (kh == 0) {
        float bb = b1[c0 + col];
#pragma unroll
        for (int r = 0; r < 8; r++) {
            tm_in[(r0 + r) * 256 + c0 + col] = sigmoidf_(acc[r] + part[r][col] + bb);
        }
    }
}

// ---------------------------------------------------------------------------
// K3: fuzzy TM clauses.  one block per window row; thread = clause.
__global__ __launch_bounds__(256) void tm_kernel(const float* __restrict__ tm_in,
                                                 const unsigned* __restrict__ mask,
                                                 float* __restrict__ clauses_ws,
                                                 float* __restrict__ clauses_out,
                                                 float* __restrict__ summary_out) {
    __shared__ float lits[512];
    __shared__ unsigned m_s[4096];  // [word(16)][clause(256)]
    __shared__ float red[256];
    int row = blockIdx.x;
    int t = threadIdx.x;
    float ti = tm_in[row * 256 + t];
    lits[t] = ti;
    lits[256 + t] = 1.0f - ti;
#pragma unroll
    for (int i = 0; i < 16; i++) m_s[i * 256 + t] = mask[i * 256 + t];
    __syncthreads();
    float m = 1.0f;
#pragma unroll
    for (int w = 0; w < 16; w++) {
        unsigned bits = m_s[w * 256 + t];
        int base = w * 32;
#pragma unroll
        for (int b = 0; b < 32; b++) {
            float lit = lits[base + b];
            float val = ((bits >> b) & 1u) ? lit : 1.0f;
            m = fminf(m, val);
        }
    }
    float hard = (m > 0.5f) ? 1.0f : 0.0f;
    clauses_ws[row * 256 + t] = hard;
    clauses_out[row * 256 + t] = hard;
    red[t] = hard;
    __syncthreads();
    for (int s = 128; s > 0; s >>= 1) {
        if (t < s) red[t] += red[t + s];
        __syncthreads();
    }
    if (t == 0) summary_out[row] = red[0] * (1.0f / 256.0f);
}

// ---------------------------------------------------------------------------
// K4: feat = sigmoid(clauses @ VW2 + b2).  M=1568, N=3072, K=256.
// Block: 8 rows x 1024 cols (4 cols/thread, float4 loads). grid (3, 196)
__global__ __launch_bounds__(256) void gemm2_kernel(const float* __restrict__ clauses,
                                                    const float* __restrict__ vw2,
                                                    const float* __restrict__ b2v,
                                                    bf16* __restrict__ feat) {
    __shared__ float c_s[8][256];
    int t = threadIdx.x;
    int r0 = blockIdx.y * 8;
    int n0 = blockIdx.x * 1024 + t * 4;
#pragma unroll
    for (int i = 0; i < 8; i++) {
        int idx = t + i * 256;
        c_s[idx >> 8][idx & 255] = clauses[(r0 + (idx >> 8)) * 256 + (idx & 255)];
    }
    __syncthreads();
    float4 acc[8];
#pragma unroll
    for (int r = 0; r < 8; r++) acc[r] = make_float4(0.f, 0.f, 0.f, 0.f);
    for (int k = 0; k < 256; k++) {
        float4 v = *reinterpret_cast<const float4*>(vw2 + k * 3072 + n0);
#pragma unroll
        for (int r = 0; r < 8; r++) {
            float s = c_s[r][k];
            acc[r].x = fmaf(s, v.x, acc[r].x);
            acc[r].y = fmaf(s, v.y, acc[r].y);
            acc[r].z = fmaf(s, v.z, acc[r].z);
            acc[r].w = fmaf(s, v.w, acc[r].w);
        }
    }
    float b0 = b2v[n0 + 0];
    float b1_ = b2v[n0 + 1];
    float b2_ = b2v[n0 + 2];
    float b3 = b2v[n0 + 3];
#pragma unroll
    for (int r = 0; r < 8; r++) {
        ushort4 pk;
        pk.x = f2bu(sigmoidf_(acc[r].x + b0));
        pk.y = f2bu(sigmoidf_(acc[r].y + b1_));
        pk.z = f2bu(sigmoidf_(acc[r].z + b2_));
        pk.w = f2bu(sigmoidf_(acc[r].w + b3));
        *reinterpret_cast<ushort4*>(feat + (r0 + r) * 3072 + n0) = pk;
    }
}

// ---------------------------------------------------------------------------
// K5: window reverse + roll(+2,+2) + gated residual
__global__ __launch_bounds__(256) void out_kernel(const float* __restrict__ x,
                                                  const bf16* __restrict__ feat,
                                                  const float* __restrict__ gate,
                                                  float* __restrict__ out) {
    int gid = blockIdx.x * 256 + threadIdx.x;  // < 4816896
    int c = gid % 192;
    int r1 = gid / 192;
    int w = r1 % 56;
    int r2 = r1 / 56;
    int h = r2 % 56;
    int b = r2 / 56;
    int hs = h - 2; if (hs < 0) hs += 56;
    int ws = w - 2; if (ws < 0) ws += 56;
    int row = b * 196 + (hs >> 2) * 14 + (ws >> 2);
    int f = ((hs & 3) * 4 + (ws & 3)) * 192 + c;
    float mv = b2f(feat[row * 3072 + f]);
    float g = sigmoidf_(gate[0]);
    float fused = g * mv + (1.0f - g) * sigmoidf_(mv);
    out[gid] = x[gid] + fused;
}

// ---------------------------------------------------------------------------
extern "C" void kernel_launch(void* const* d_in, const int* in_sizes, int n_in,
                              void* d_out, int out_size, void* d_ws, size_t ws_size,
                              hipStream_t stream) {
    const float* x      = (const float*)d_in[0];
    const float* gamma  = (const float*)d_in[1];
    const float* beta   = (const float*)d_in[2];
    const float* W1     = (const float*)d_in[3];
    const float* b1     = (const float*)d_in[4];
    const float* inc_w  = (const float*)d_in[5];
    const float* vote_w = (const float*)d_in[6];
    const float* W2     = (const float*)d_in[7];
    const float* b2v    = (const float*)d_in[8];
    const float* gate   = (const float*)d_in[9];

    char* ws = (char*)d_ws;
    // workspace carve (bytes):
    bf16*     win     = (bf16*)(ws + 0);            // 1568*3072*2  = 9,633,792
    float*    tm_in   = (float*)(ws + 9633792);     // 1568*256*4   = 1,605,632
    float*    clauses = (float*)(ws + 11239424);    // 1568*256*4   = 1,605,632
    float*    vw2     = (float*)(ws + 12845056);    // 256*3072*4   = 3,145,728
    bf16*     feat    = (bf16*)(ws + 15990784);     // 1568*3072*2  = 9,633,792
    unsigned* mask    = (unsigned*)(ws + 25624576); // 16,384  (total ~25.6 MB)

    float* out     = (float*)d_out;
    float* cl_out  = out + 4816896;            // clauses: 1568*256
    float* sum_out = cl_out + 401408;          // summary: 1568

    inc_mask_kernel<<<16, 256, 0, stream>>>(inc_w, mask);
    vw2_kernel<<<dim3(12, 256), 256, 0, stream>>>(vote_w, W2, vw2);
    ln_win_kernel<<<25088, 64, 0, stream>>>(x, gamma, beta, win);
    gemm1_kernel<<<dim3(2, 196), 256, 0, stream>>>(win, W1, b1, tm_in);
    tm_kernel<<<1568, 256, 0, stream>>>(tm_in, mask, clauses, cl_out, sum_out);
    gemm2_kernel<<<dim3(3, 196), 256, 0, stream>>>(clauses, vw2, b2v, feat);
    out_kernel<<<18816, 256, 0, stream>>>(x, feat, gate, out);
}

// Round 3
// 254.255 us; speedup vs baseline: 2.5326x; 2.5326x over previous
//
#include <hip/hip_runtime.h>
#include <hip/hip_bf16.h>

typedef __hip_bfloat16 bf16;
typedef __attribute__((ext_vector_type(8))) short short8;
typedef __attribute__((ext_vector_type(4))) float floatx4;

#define DEVI __device__ __forceinline__

DEVI float b2f(bf16 v) { return __bfloat162float(v); }
DEVI bf16 f2b(float v) { return __float2bfloat16(v); }
DEVI unsigned short f2bu(float v) {
    bf16 h = __float2bfloat16(v);
    unsigned short u;
    __builtin_memcpy(&u, &h, 2);
    return u;
}
DEVI float sigmoidf_(float z) { return 1.0f / (1.0f + __expf(-z)); }

// Problem constants
// B=8, H=W=56, C=192, WS=4 -> 14x14 windows, 1568 rows, ind=3072, hid=ncl=256
// ALL inputs/outputs are float32.

// ---------------------------------------------------------------------------
// K0a: inc bitmask.  inc = (inc_w > 0).  mask layout: [word(16)][clause(256)]
__global__ __launch_bounds__(256) void inc_mask_kernel(const float* __restrict__ inc_w,
                                                       unsigned* __restrict__ mask) {
    int wi = blockIdx.x;   // 0..15
    int cl = threadIdx.x;  // 0..255
    unsigned bits = 0u;
    int base = cl * 512 + wi * 32;
#pragma unroll
    for (int b = 0; b < 32; b++) {
        if (inc_w[base + b] > 0.0f) bits |= (1u << b);
    }
    mask[wi * 256 + cl] = bits;
}

// ---------------------------------------------------------------------------
// K0b: VW2 = vote_w @ W2 / 16   (256 x 3072, K=192), fp32 out
__global__ __launch_bounds__(256) void vw2_kernel(const float* __restrict__ vote_w,
                                                  const float* __restrict__ W2,
                                                  float* __restrict__ vw2) {
    int n = blockIdx.x * 256 + threadIdx.x;  // 0..3071
    int k = blockIdx.y;                      // 0..255
    float acc = 0.0f;
    for (int j = 0; j < 192; j++) {
        acc = fmaf(vote_w[k * 192 + j], W2[j * 3072 + n], acc);
    }
    vw2[k * 3072 + n] = acc * 0.0625f;  // 1/sqrt(256)
}

// ---------------------------------------------------------------------------
// K0c: repack W1 (3072x256 f32, row-major) into bf16 B-fragment layout for
// mfma_f32_16x16x32_bf16:  B[k][n] -> w1frag[((nb*96 + kb)*64 + lane)*8 + j]
// with nb=n>>4, kb=k>>5, lane=((k>>3)&3)*16 + (n&15), j=k&7.
// Each B fragment (one 16-wide n-tile, one 32-deep k-step) is then a single
// coalesced 16B/lane global load.
__global__ __launch_bounds__(256) void w1frag_kernel(const float* __restrict__ W1,
                                                     unsigned short* __restrict__ w1frag) {
    int k = blockIdx.x;   // 0..3071
    int n = threadIdx.x;  // 0..255
    int nb = n >> 4;
    int lane = ((k >> 3) & 3) * 16 + (n & 15);
    int off = ((nb * 96 + (k >> 5)) * 64 + lane) * 8 + (k & 7);
    w1frag[off] = f2bu(W1[k * 256 + n]);
}

// ---------------------------------------------------------------------------
// K1: LayerNorm + roll(-2,-2) + window partition -> win (1568 x 3072) bf16
__global__ __launch_bounds__(64) void ln_win_kernel(const float* __restrict__ x,
                                                    const float* __restrict__ gamma,
                                                    const float* __restrict__ beta,
                                                    bf16* __restrict__ win) {
    int blk = blockIdx.x;          // b*3136 + h'*56 + w'  (rolled coords)
    int w_ = blk % 56;
    int t2 = blk / 56;
    int h_ = t2 % 56;
    int b = t2 / 56;
    int hs = h_ + 2; if (hs >= 56) hs -= 56;
    int ws = w_ + 2; if (ws >= 56) ws -= 56;
    const float* xp = x + (((b * 56 + hs) * 56 + ws) * 192);
    int t = threadIdx.x;  // 0..63
    float v0 = xp[t];
    float v1 = xp[t + 64];
    float v2 = xp[t + 128];
    float s = v0 + v1 + v2;
    float sq = v0 * v0 + v1 * v1 + v2 * v2;
#pragma unroll
    for (int m = 1; m < 64; m <<= 1) {
        s += __shfl_xor(s, m, 64);
        sq += __shfl_xor(sq, m, 64);
    }
    float mean = s * (1.0f / 192.0f);
    float var = sq * (1.0f / 192.0f) - mean * mean;
    float inv = rsqrtf(var + 1e-5f);
    int row = b * 196 + (h_ >> 2) * 14 + (w_ >> 2);
    int fb = ((h_ & 3) * 4 + (w_ & 3)) * 192;
    bf16* wp = win + row * 3072 + fb;
    wp[t]       = f2b((v0 - mean) * inv * gamma[t]       + beta[t]);
    wp[t + 64]  = f2b((v1 - mean) * inv * gamma[t + 64]  + beta[t + 64]);
    wp[t + 128] = f2b((v2 - mean) * inv * gamma[t + 128] + beta[t + 128]);
}

// ---------------------------------------------------------------------------
// K2: tm_in = sigmoid(win @ W1 + b1).  M=1568, N=256, K=3072.
// MFMA 16x16x32 bf16, no LDS, no barriers.  Block = 4 waves as 2m x 2n
// (block tile 32x32); grid (49 m, 8 n) = 392 blocks.
// A frag: A[m=lane&15][k=quad*8+j] -> 16B contiguous per lane from win rows.
// B frag: one global_load_dwordx4 per lane from pre-swizzled w1frag.
// D: row = quad*4 + reg, col = lane&15 (m89/m91-verified layout).
__global__ __launch_bounds__(256) void gemm1_mfma(const bf16* __restrict__ win,
                                                  const unsigned short* __restrict__ w1frag,
                                                  const float* __restrict__ b1,
                                                  float* __restrict__ tm_in) {
    int t = threadIdx.x;
    int wave = t >> 6;
    int lane = t & 63;
    int quad = lane >> 4;
    int mlo = lane & 15;
    int wm = wave & 1;
    int wn = wave >> 1;
    int m0 = blockIdx.x * 32 + wm * 16;
    int nb = blockIdx.y * 2 + wn;  // 16-wide n-tile index, 0..15

    const bf16* ap = win + (m0 + mlo) * 3072 + quad * 8;
    const unsigned short* bp = w1frag + (size_t)nb * 96 * 512 + lane * 8;

    floatx4 acc = {0.f, 0.f, 0.f, 0.f};
#pragma unroll 4
    for (int kb = 0; kb < 96; kb++) {
        short8 a = *reinterpret_cast<const short8*>(ap + kb * 32);
        short8 b = *reinterpret_cast<const short8*>(bp + kb * 512);
        acc = __builtin_amdgcn_mfma_f32_16x16x32_bf16(a, b, acc, 0, 0, 0);
    }

    int n_g = nb * 16 + mlo;
    float bb = b1[n_g];
#pragma unroll
    for (int r = 0; r < 4; r++) {
        int m_g = m0 + quad * 4 + r;
        tm_in[m_g * 256 + n_g] = sigmoidf_(acc[r] + bb);
    }
}

// ---------------------------------------------------------------------------
// K3: fuzzy TM clauses.  one block per window row; thread = clause.
__global__ __launch_bounds__(256) void tm_kernel(const float* __restrict__ tm_in,
                                                 const unsigned* __restrict__ mask,
                                                 float* __restrict__ clauses_ws,
                                                 float* __restrict__ clauses_out,
                                                 float* __restrict__ summary_out) {
    __shared__ float lits[512];
    __shared__ unsigned m_s[4096];
    __shared__ float red[256];
    int row = blockIdx.x;
    int t = threadIdx.x;
    float ti = tm_in[row * 256 + t];
    lits[t] = ti;
    lits[256 + t] = 1.0f - ti;
#pragma unroll
    for (int i = 0; i < 16; i++) m_s[i * 256 + t] = mask[i * 256 + t];
    __syncthreads();
    float m = 1.0f;
#pragma unroll
    for (int w = 0; w < 16; w++) {
        unsigned bits = m_s[w * 256 + t];
        int base = w * 32;
#pragma unroll
        for (int b = 0; b < 32; b++) {
            float lit = lits[base + b];
            float val = ((bits >> b) & 1u) ? lit : 1.0f;
            m = fminf(m, val);
        }
    }
    float hard = (m > 0.5f) ? 1.0f : 0.0f;
    clauses_ws[row * 256 + t] = hard;
    clauses_out[row * 256 + t] = hard;
    red[t] = hard;
    __syncthreads();
    for (int s = 128; s > 0; s >>= 1) {
        if (t < s) red[t] += red[t + s];
        __syncthreads();
    }
    if (t == 0) summary_out[row] = red[0] * (1.0f / 256.0f);
}

// ---------------------------------------------------------------------------
// K4: feat = sigmoid(clauses @ VW2 + b2).  M=1568, N=3072, K=256.
__global__ __launch_bounds__(256) void gemm2_kernel(const float* __restrict__ clauses,
                                                    const float* __restrict__ vw2,
                                                    const float* __restrict__ b2v,
                                                    bf16* __restrict__ feat) {
    __shared__ float c_s[8][256];
    int t = threadIdx.x;
    int r0 = blockIdx.y * 8;
    int n0 = blockIdx.x * 1024 + t * 4;
#pragma unroll
    for (int i = 0; i < 8; i++) {
        int idx = t + i * 256;
        c_s[idx >> 8][idx & 255] = clauses[(r0 + (idx >> 8)) * 256 + (idx & 255)];
    }
    __syncthreads();
    float4 acc[8];
#pragma unroll
    for (int r = 0; r < 8; r++) acc[r] = make_float4(0.f, 0.f, 0.f, 0.f);
    for (int k = 0; k < 256; k++) {
        float4 v = *reinterpret_cast<const float4*>(vw2 + k * 3072 + n0);
#pragma unroll
        for (int r = 0; r < 8; r++) {
            float s = c_s[r][k];
            acc[r].x = fmaf(s, v.x, acc[r].x);
            acc[r].y = fmaf(s, v.y, acc[r].y);
            acc[r].z = fmaf(s, v.z, acc[r].z);
            acc[r].w = fmaf(s, v.w, acc[r].w);
        }
    }
    float b0 = b2v[n0 + 0];
    float b1_ = b2v[n0 + 1];
    float b2_ = b2v[n0 + 2];
    float b3 = b2v[n0 + 3];
#pragma unroll
    for (int r = 0; r < 8; r++) {
        ushort4 pk;
        pk.x = f2bu(sigmoidf_(acc[r].x + b0));
        pk.y = f2bu(sigmoidf_(acc[r].y + b1_));
        pk.z = f2bu(sigmoidf_(acc[r].z + b2_));
        pk.w = f2bu(sigmoidf_(acc[r].w + b3));
        *reinterpret_cast<ushort4*>(feat + (r0 + r) * 3072 + n0) = pk;
    }
}

// ---------------------------------------------------------------------------
// K5: window reverse + roll(+2,+2) + gated residual
__global__ __launch_bounds__(256) void out_kernel(const float* __restrict__ x,
                                                  const bf16* __restrict__ feat,
                                                  const float* __restrict__ gate,
                                                  float* __restrict__ out) {
    int gid = blockIdx.x * 256 + threadIdx.x;  // < 4816896
    int c = gid % 192;
    int r1 = gid / 192;
    int w = r1 % 56;
    int r2 = r1 / 56;
    int h = r2 % 56;
    int b = r2 / 56;
    int hs = h - 2; if (hs < 0) hs += 56;
    int ws = w - 2; if (ws < 0) ws += 56;
    int row = b * 196 + (hs >> 2) * 14 + (ws >> 2);
    int f = ((hs & 3) * 4 + (ws & 3)) * 192 + c;
    float mv = b2f(feat[row * 3072 + f]);
    float g = sigmoidf_(gate[0]);
    float fused = g * mv + (1.0f - g) * sigmoidf_(mv);
    out[gid] = x[gid] + fused;
}

// ---------------------------------------------------------------------------
extern "C" void kernel_launch(void* const* d_in, const int* in_sizes, int n_in,
                              void* d_out, int out_size, void* d_ws, size_t ws_size,
                              hipStream_t stream) {
    const float* x      = (const float*)d_in[0];
    const float* gamma  = (const float*)d_in[1];
    const float* beta   = (const float*)d_in[2];
    const float* W1     = (const float*)d_in[3];
    const float* b1     = (const float*)d_in[4];
    const float* inc_w  = (const float*)d_in[5];
    const float* vote_w = (const float*)d_in[6];
    const float* W2     = (const float*)d_in[7];
    const float* b2v    = (const float*)d_in[8];
    const float* gate   = (const float*)d_in[9];

    char* ws = (char*)d_ws;
    // workspace carve (bytes):
    bf16*     win     = (bf16*)(ws + 0);            // 1568*3072*2  = 9,633,792
    float*    tm_in   = (float*)(ws + 9633792);     // 1568*256*4   = 1,605,632
    float*    clauses = (float*)(ws + 11239424);    // 1568*256*4   = 1,605,632
    float*    vw2     = (float*)(ws + 12845056);    // 256*3072*4   = 3,145,728
    bf16*     feat    = (bf16*)(ws + 15990784);     // 1568*3072*2  = 9,633,792
    unsigned* mask    = (unsigned*)(ws + 25624576); // 16,384  (total ~25.6 MB)
    // w1frag (1,572,864 B) aliases the clauses region: written by w1frag_kernel,
    // read only by gemm1_mfma, dead before tm_kernel writes clauses. Stream-ordered.
    unsigned short* w1frag = (unsigned short*)(ws + 11239424);

    float* out     = (float*)d_out;
    float* cl_out  = out + 4816896;            // clauses: 1568*256
    float* sum_out = cl_out + 401408;          // summary: 1568

    inc_mask_kernel<<<16, 256, 0, stream>>>(inc_w, mask);
    vw2_kernel<<<dim3(12, 256), 256, 0, stream>>>(vote_w, W2, vw2);
    w1frag_kernel<<<3072, 256, 0, stream>>>(W1, w1frag);
    ln_win_kernel<<<25088, 64, 0, stream>>>(x, gamma, beta, win);
    gemm1_mfma<<<dim3(49, 8), 256, 0, stream>>>(win, w1frag, b1, tm_in);
    tm_kernel<<<1568, 256, 0, stream>>>(tm_in, mask, clauses, cl_out, sum_out);
    gemm2_kernel<<<dim3(3, 196), 256, 0, stream>>>(clauses, vw2, b2v, feat);
    out_kernel<<<18816, 256, 0, stream>>>(x, feat, gate, out);
}

// Round 4
// 186.399 us; speedup vs baseline: 3.4546x; 1.3640x over previous
//
#include <hip/hip_runtime.h>
#include <hip/hip_bf16.h>

typedef __hip_bfloat16 bf16;
typedef __attribute__((ext_vector_type(8))) short short8;
typedef __attribute__((ext_vector_type(4))) float floatx4;

#define DEVI __device__ __forceinline__

DEVI float b2f(bf16 v) { return __bfloat162float(v); }
DEVI bf16 f2b(float v) { return __float2bfloat16(v); }
DEVI unsigned short f2bu(float v) {
    bf16 h = __float2bfloat16(v);
    unsigned short u;
    __builtin_memcpy(&u, &h, 2);
    return u;
}
DEVI float sigmoidf_(float z) { return 1.0f / (1.0f + __expf(-z)); }

// Problem constants
// B=8, H=W=56, C=192, WS=4 -> 14x14 windows, 1568 rows, ind=3072, hid=ncl=256
// ALL inputs/outputs are float32.
//
// MFMA fragment conventions (mfma_f32_16x16x32_bf16, verified in R2/R3):
//   A[m][k]: lane = quad*16 + m15 -> m = m15, k = quad*8 + j   (16B contiguous)
//   B[k][n]: lane = quad*16 + n15 -> k = quad*8 + j, n = n15
//   D[m][n]: col n = lane&15, row m = quad*4 + reg

// ---------------------------------------------------------------------------
// K0a: inc bitmask.  inc = (inc_w > 0).  mask layout: [word(16)][clause(256)]
__global__ __launch_bounds__(256) void inc_mask_kernel(const float* __restrict__ inc_w,
                                                       unsigned* __restrict__ mask) {
    int wi = blockIdx.x;   // 0..15
    int cl = threadIdx.x;  // 0..255
    unsigned bits = 0u;
    int base = cl * 512 + wi * 32;
#pragma unroll
    for (int b = 0; b < 32; b++) {
        if (inc_w[base + b] > 0.0f) bits |= (1u << b);
    }
    mask[wi * 256 + cl] = bits;
}

// ---------------------------------------------------------------------------
// K0b: vw2 = vote_w @ W2 / 16  (256 x 3072, K=192), written DIRECTLY as bf16
// B-fragment layout for gemm2_mfma. k-tiled (8 k per block) so each W2 element
// is loaded once per 8 k-values (W2 L2 traffic /8 vs R3).
__global__ __launch_bounds__(256) void vw2_kernel(const float* __restrict__ vote_w,
                                                  const float* __restrict__ W2,
                                                  unsigned short* __restrict__ vw2frag) {
    int n = blockIdx.x * 256 + threadIdx.x;  // 0..3071
    int k0 = blockIdx.y * 8;                 // 0..255 step 8
    float acc[8];
#pragma unroll
    for (int kk = 0; kk < 8; kk++) acc[kk] = 0.0f;
    for (int j = 0; j < 192; j++) {
        float w = W2[j * 3072 + n];
#pragma unroll
        for (int kk = 0; kk < 8; kk++) {
            acc[kk] = fmaf(vote_w[(k0 + kk) * 192 + j], w, acc[kk]);  // uniform -> s_load
        }
    }
    int nb = n >> 4;
#pragma unroll
    for (int kk = 0; kk < 8; kk++) {
        int k = k0 + kk;
        int lane = ((k >> 3) & 3) * 16 + (n & 15);
        int off = ((nb * 8 + (k >> 5)) * 64 + lane) * 8 + (k & 7);
        vw2frag[off] = f2bu(acc[kk] * 0.0625f);  // 1/sqrt(256)
    }
}

// ---------------------------------------------------------------------------
// K0c: repack W1 (3072x256 f32) into bf16 B-fragment layout (16x16x32 tiles).
__global__ __launch_bounds__(256) void w1frag_kernel(const float* __restrict__ W1,
                                                     unsigned short* __restrict__ w1frag) {
    int k = blockIdx.x;   // 0..3071
    int n = threadIdx.x;  // 0..255
    int nb = n >> 4;
    int lane = ((k >> 3) & 3) * 16 + (n & 15);
    int off = ((nb * 96 + (k >> 5)) * 64 + lane) * 8 + (k & 7);
    w1frag[off] = f2bu(W1[k * 256 + n]);
}

// ---------------------------------------------------------------------------
// K1: LayerNorm + roll(-2,-2) + window partition -> win (1568 x 3072) bf16
__global__ __launch_bounds__(64) void ln_win_kernel(const float* __restrict__ x,
                                                    const float* __restrict__ gamma,
                                                    const float* __restrict__ beta,
                                                    bf16* __restrict__ win) {
    int blk = blockIdx.x;          // b*3136 + h'*56 + w'  (rolled coords)
    int w_ = blk % 56;
    int t2 = blk / 56;
    int h_ = t2 % 56;
    int b = t2 / 56;
    int hs = h_ + 2; if (hs >= 56) hs -= 56;
    int ws = w_ + 2; if (ws >= 56) ws -= 56;
    const float* xp = x + (((b * 56 + hs) * 56 + ws) * 192);
    int t = threadIdx.x;  // 0..63
    float v0 = xp[t];
    float v1 = xp[t + 64];
    float v2 = xp[t + 128];
    float s = v0 + v1 + v2;
    float sq = v0 * v0 + v1 * v1 + v2 * v2;
#pragma unroll
    for (int m = 1; m < 64; m <<= 1) {
        s += __shfl_xor(s, m, 64);
        sq += __shfl_xor(sq, m, 64);
    }
    float mean = s * (1.0f / 192.0f);
    float var = sq * (1.0f / 192.0f) - mean * mean;
    float inv = rsqrtf(var + 1e-5f);
    int row = b * 196 + (h_ >> 2) * 14 + (w_ >> 2);
    int fb = ((h_ & 3) * 4 + (w_ & 3)) * 192;
    bf16* wp = win + row * 3072 + fb;
    wp[t]       = f2b((v0 - mean) * inv * gamma[t]       + beta[t]);
    wp[t + 64]  = f2b((v1 - mean) * inv * gamma[t + 64]  + beta[t + 64]);
    wp[t + 128] = f2b((v2 - mean) * inv * gamma[t + 128] + beta[t + 128]);
}

// ---------------------------------------------------------------------------
// K2: tm_in = sigmoid(win @ W1 + b1).  M=1568, N=256, K=3072.
// MFMA 16x16x32 bf16, no LDS, no barriers.  grid (49 m, 8 n), 4 waves 2m x 2n.
__global__ __launch_bounds__(256) void gemm1_mfma(const bf16* __restrict__ win,
                                                  const unsigned short* __restrict__ w1frag,
                                                  const float* __restrict__ b1,
                                                  float* __restrict__ tm_in) {
    int t = threadIdx.x;
    int wave = t >> 6;
    int lane = t & 63;
    int quad = lane >> 4;
    int mlo = lane & 15;
    int wm = wave & 1;
    int wn = wave >> 1;
    int m0 = blockIdx.x * 32 + wm * 16;
    int nb = blockIdx.y * 2 + wn;  // 16-wide n-tile index, 0..15

    const bf16* ap = win + (m0 + mlo) * 3072 + quad * 8;
    const unsigned short* bp = w1frag + (size_t)nb * 96 * 512 + lane * 8;

    floatx4 acc = {0.f, 0.f, 0.f, 0.f};
#pragma unroll 4
    for (int kb = 0; kb < 96; kb++) {
        short8 a = *reinterpret_cast<const short8*>(ap + kb * 32);
        short8 b = *reinterpret_cast<const short8*>(bp + kb * 512);
        acc = __builtin_amdgcn_mfma_f32_16x16x32_bf16(a, b, acc, 0, 0, 0);
    }

    int n_g = nb * 16 + mlo;
    float bb = b1[n_g];
#pragma unroll
    for (int r = 0; r < 4; r++) {
        int m_g = m0 + quad * 4 + r;
        tm_in[m_g * 256 + n_g] = sigmoidf_(acc[r] + bb);
    }
}

// ---------------------------------------------------------------------------
// K3: clauses via bitwise AND.  clause = (min over included lits > 0.5)
//                              = AND over included lits of (lit > 0.5).
// g bits per row: lits 0..255 = (x>0.5), lits 256..511 = (x<0.5). One block/row.
__global__ __launch_bounds__(256) void tm_kernel(const float* __restrict__ tm_in,
                                                 const unsigned* __restrict__ mask,
                                                 float* __restrict__ cl_out,
                                                 bf16* __restrict__ clauses_bf,
                                                 float* __restrict__ sum_out) {
    __shared__ unsigned g_s[16];
    __shared__ float red[4];
    int row = blockIdx.x;
    int t = threadIdx.x;
    int wave = t >> 6;
    int lane = t & 63;
    float xv = tm_in[row * 256 + t];
    unsigned long long bhi = __ballot(xv > 0.5f);  // lit t
    unsigned long long blo = __ballot(xv < 0.5f);  // lit 256+t
    if (lane == 0) {
        g_s[wave * 2]     = (unsigned)bhi;
        g_s[wave * 2 + 1] = (unsigned)(bhi >> 32);
        g_s[8 + wave * 2]     = (unsigned)blo;
        g_s[8 + wave * 2 + 1] = (unsigned)(blo >> 32);
    }
    __syncthreads();
    unsigned ok = 1u;
#pragma unroll
    for (int w = 0; w < 16; w++) {
        unsigned viol = (~g_s[w]) & mask[w * 256 + t];
        ok &= (viol == 0u) ? 1u : 0u;
    }
    float hard = (float)ok;
    cl_out[row * 256 + t] = hard;
    clauses_bf[row * 256 + t] = f2b(hard);
    unsigned long long cb = __ballot(ok != 0u);
    if (lane == 0) red[wave] = (float)__popcll(cb);
    __syncthreads();
    if (t == 0) sum_out[row] = (red[0] + red[1] + red[2] + red[3]) * (1.0f / 256.0f);
}

// ---------------------------------------------------------------------------
// K4: feat = sigmoid(clauses @ vw2 + b2).  M=1568, N=3072, K=256.
// MFMA, no LDS/barriers.  Block 4 waves: 2m x 2n-halves; wave tile 16m x 64n
// (4 acc tiles).  grid (49 m, 24 n128).
__global__ __launch_bounds__(256) void gemm2_mfma(const bf16* __restrict__ clauses_bf,
                                                  const unsigned short* __restrict__ vw2frag,
                                                  const float* __restrict__ b2v,
                                                  bf16* __restrict__ feat) {
    int t = threadIdx.x;
    int wave = t >> 6;
    int lane = t & 63;
    int quad = lane >> 4;
    int mlo = lane & 15;
    int wm = wave & 1;
    int wn = wave >> 1;
    int m0 = blockIdx.x * 32 + wm * 16;
    int nb0 = blockIdx.y * 8 + wn * 4;  // 16-wide n-tile base

    const bf16* ap = clauses_bf + (m0 + mlo) * 256 + quad * 8;
    const unsigned short* bp = vw2frag + lane * 8;

    floatx4 acc[4];
#pragma unroll
    for (int i = 0; i < 4; i++) acc[i] = (floatx4){0.f, 0.f, 0.f, 0.f};

#pragma unroll
    for (int kb = 0; kb < 8; kb++) {
        short8 a = *reinterpret_cast<const short8*>(ap + kb * 32);
#pragma unroll
        for (int i = 0; i < 4; i++) {
            short8 b = *reinterpret_cast<const short8*>(bp + ((nb0 + i) * 8 + kb) * 512);
            acc[i] = __builtin_amdgcn_mfma_f32_16x16x32_bf16(a, b, acc[i], 0, 0, 0);
        }
    }

#pragma unroll
    for (int i = 0; i < 4; i++) {
        int n_g = (nb0 + i) * 16 + mlo;
        float bb = b2v[n_g];
#pragma unroll
        for (int r = 0; r < 4; r++) {
            int m_g = m0 + quad * 4 + r;
            feat[m_g * 3072 + n_g] = f2b(sigmoidf_(acc[i][r] + bb));
        }
    }
}

// ---------------------------------------------------------------------------
// K5: window reverse + roll(+2,+2) + gated residual
__global__ __launch_bounds__(256) void out_kernel(const float* __restrict__ x,
                                                  const bf16* __restrict__ feat,
                                                  const float* __restrict__ gate,
                                                  float* __restrict__ out) {
    int gid = blockIdx.x * 256 + threadIdx.x;  // < 4816896
    int c = gid % 192;
    int r1 = gid / 192;
    int w = r1 % 56;
    int r2 = r1 / 56;
    int h = r2 % 56;
    int b = r2 / 56;
    int hs = h - 2; if (hs < 0) hs += 56;
    int ws = w - 2; if (ws < 0) ws += 56;
    int row = b * 196 + (hs >> 2) * 14 + (ws >> 2);
    int f = ((hs & 3) * 4 + (ws & 3)) * 192 + c;
    float mv = b2f(feat[row * 3072 + f]);
    float g = sigmoidf_(gate[0]);
    float fused = g * mv + (1.0f - g) * sigmoidf_(mv);
    out[gid] = x[gid] + fused;
}

// ---------------------------------------------------------------------------
extern "C" void kernel_launch(void* const* d_in, const int* in_sizes, int n_in,
                              void* d_out, int out_size, void* d_ws, size_t ws_size,
                              hipStream_t stream) {
    const float* x      = (const float*)d_in[0];
    const float* gamma  = (const float*)d_in[1];
    const float* beta   = (const float*)d_in[2];
    const float* W1     = (const float*)d_in[3];
    const float* b1     = (const float*)d_in[4];
    const float* inc_w  = (const float*)d_in[5];
    const float* vote_w = (const float*)d_in[6];
    const float* W2     = (const float*)d_in[7];
    const float* b2v    = (const float*)d_in[8];
    const float* gate   = (const float*)d_in[9];

    char* ws = (char*)d_ws;
    // workspace carve (bytes), total 25,640,960 (same footprint as R3):
    bf16*           win        = (bf16*)(ws + 0);                  // 9,633,792
    float*          tm_in      = (float*)(ws + 9633792);           // 1,605,632
    unsigned short* w1frag     = (unsigned short*)(ws + 11239424); // 1,572,864 (dead after gemm1)
    unsigned short* vw2frag    = (unsigned short*)(ws + 12845056); // 1,572,864
    bf16*           clauses_bf = (bf16*)(ws + 14417920);           //   802,816
    bf16*           feat       = (bf16*)(ws + 15990784);           // 9,633,792
    unsigned*       mask       = (unsigned*)(ws + 25624576);       //    16,384

    float* out     = (float*)d_out;
    float* cl_out  = out + 4816896;            // clauses: 1568*256
    float* sum_out = cl_out + 401408;          // summary: 1568

    inc_mask_kernel<<<16, 256, 0, stream>>>(inc_w, mask);
    vw2_kernel<<<dim3(12, 32), 256, 0, stream>>>(vote_w, W2, vw2frag);
    w1frag_kernel<<<3072, 256, 0, stream>>>(W1, w1frag);
    ln_win_kernel<<<25088, 64, 0, stream>>>(x, gamma, beta, win);
    gemm1_mfma<<<dim3(49, 8), 256, 0, stream>>>(win, w1frag, b1, tm_in);
    tm_kernel<<<1568, 256, 0, stream>>>(tm_in, mask, cl_out, clauses_bf, sum_out);
    gemm2_mfma<<<dim3(49, 24), 256, 0, stream>>>(clauses_bf, vw2frag, b2v, feat);
    out_kernel<<<18816, 256, 0, stream>>>(x, feat, gate, out);
}